// Round 2
// baseline (273.930 us; speedup 1.0000x reference)
//
#include <hip/hip_runtime.h>
#include <hip/hip_bf16.h>
#include <math.h>

typedef __attribute__((ext_vector_type(8))) short short8v;
typedef __attribute__((ext_vector_type(4))) short short4v;
typedef __attribute__((ext_vector_type(4))) float float4v;
typedef unsigned short u16;

#define BATCH 32768
#define PAGES 4096
#define QB 128          // queries per block (4 waves x 32)
#define QS_LD 136       // u16, 272B rows -> 16B aligned

__device__ __forceinline__ u16 f2bf(float f) {
  __hip_bfloat16 h = __float2bfloat16(f);
  union { __hip_bfloat16 h; u16 u; } cv; cv.h = h; return cv.u;
}
__device__ __forceinline__ float bf2f(u16 b) {
  union { u16 u; __hip_bfloat16 h; } cv; cv.u = b; return __bfloat162float(cv.h);
}
__device__ __forceinline__ float sigm(float x) { return 1.0f / (1.0f + __expf(-x)); }

__device__ __forceinline__ void gl_lds16(const void* g, void* l) {
  __builtin_amdgcn_global_load_lds(
      (const __attribute__((address_space(1))) unsigned int*)g,
      (__attribute__((address_space(3))) unsigned int*)l, 16, 0, 0);
}

// ---------------------------------------------------------------------------
// prep (merged): blocks [0,256): K-side; blocks [256,768): V-side.
// K layout [4096][128] bf16, chunk c stored at c^(p&7) (XOR swizzle baked in):
//   d 0..63   : page_keys
//   d 64..103 : hi(4*sigmoid(vp))  (duplicated twice)
//   d 104..123: lo(4*sigmoid(vp))
//   d 124,125 : hi(cb), d 126: lo(cb), d 127: 0     cb = -2*sum(sigmoid(vp)^2)
// (Q carries c2=log2e/temp in dims 124..126, so logits come out of the MFMA
//  already scaled and biased.)
// Vt [32][4096] bf16, pages permuted within 64-groups: s=(p&15)*4+((p>>4)&3).
// ---------------------------------------------------------------------------
__global__ __launch_bounds__(256) void prep(const float* __restrict__ pk,
                                            const float* __restrict__ vp,
                                            const float* __restrict__ ph,
                                            const float* __restrict__ pr,
                                            u16* __restrict__ Kg,
                                            u16* __restrict__ Vtg) {
  if (blockIdx.x < 256) {
    int tg = blockIdx.x * 256 + threadIdx.x;   // (page, chunk)
    int p = tg >> 4, c = tg & 15;
    float cb = 0.0f;
    if (c == 15) {
#pragma unroll
      for (int j = 0; j < 20; ++j) { float s = sigm(vp[p * 20 + j]); cb += s * s; }
      cb *= -2.0f;
    }
    short8v vals;
#pragma unroll
    for (int e = 0; e < 8; ++e) {
      int d = c * 8 + e;
      u16 bits;
      if (d < 64) {
        bits = f2bf(pk[p * 64 + d]);
      } else if (d < 124) {
        int j = (d - 64) % 20;
        float s4 = 4.0f * sigm(vp[p * 20 + j]);
        u16 hi = f2bf(s4);
        bits = (d < 104) ? hi : f2bf(s4 - bf2f(hi));
      } else if (d < 126) {
        bits = f2bf(cb);
      } else if (d == 126) {
        u16 hi = f2bf(cb);
        bits = f2bf(cb - bf2f(hi));
      } else {
        bits = 0;
      }
      vals[e] = (short)bits;
    }
    int cs = c ^ (p & 7);
    *reinterpret_cast<short8v*>(&Kg[p * 128 + cs * 8]) = vals;
  } else {
    int tg = (blockIdx.x - 256) * 256 + threadIdx.x;   // (vcol, page)
    int p = tg & 4095, v = tg >> 12;
    float x;
    if (v < 20) x = sigm(ph[p * 20 + v]);
    else if (v < 24) x = sigm(pr[p * 4 + (v - 20)]);
    else x = 0.0f;
    int s = (p & 15) * 4 + ((p >> 4) & 3);
    Vtg[v * 4096 + (p & ~63) + s] = f2bf(x);
  }
}

// ---------------------------------------------------------------------------
// QK for one 64-page tile from LDS buffer Kb into acc (2 query-halves x 4 ct).
// ---------------------------------------------------------------------------
__device__ __forceinline__ void readqk(const u16* __restrict__ Kb,
                                       const short8v (&qf)[2][4],
                                       float4v (&A)[2][4], int li, int g) {
#pragma unroll
  for (int ct = 0; ct < 4; ++ct) {
    A[0][ct] = (float4v){0.f, 0.f, 0.f, 0.f};
    A[1][ct] = (float4v){0.f, 0.f, 0.f, 0.f};
#pragma unroll
    for (int ks = 0; ks < 4; ++ks) {
      short8v b = *reinterpret_cast<const short8v*>(
          &Kb[(ct * 16 + li) * 128 + (((ks * 4 + g) ^ (li & 7)) << 3)]);
      A[0][ct] = __builtin_amdgcn_mfma_f32_16x16x32_bf16(qf[0][ks], b, A[0][ct], 0, 0, 0);
      A[1][ct] = __builtin_amdgcn_mfma_f32_16x16x32_bf16(qf[1][ks], b, A[1][ct], 0, 0, 0);
    }
  }
}

// ---------------------------------------------------------------------------
// Online softmax (defer-max, THR=8) + PV for one tile.
// ---------------------------------------------------------------------------
__device__ __forceinline__ void smpv(float4v (&A)[2][4], float (&m_run)[2][4],
                                     float (&lsum)[2][4], float4v (&Ov)[2][2],
                                     u16* __restrict__ Psw, const u16* __restrict__ Vtg,
                                     int tn, int li, int g) {
  float rmax[2][4];
#pragma unroll
  for (int h = 0; h < 2; ++h)
#pragma unroll
    for (int r = 0; r < 4; ++r)
      rmax[h][r] = fmaxf(fmaxf(A[h][0][r], A[h][1][r]), fmaxf(A[h][2][r], A[h][3][r]));

  float d = -1e30f;
#pragma unroll
  for (int h = 0; h < 2; ++h)
#pragma unroll
    for (int r = 0; r < 4; ++r) d = fmaxf(d, rmax[h][r] - m_run[h][r]);

  if (!__all(d <= 8.0f)) {               // rare: true rescale
#pragma unroll
    for (int msk = 1; msk <= 8; msk <<= 1)
#pragma unroll
      for (int h = 0; h < 2; ++h)
#pragma unroll
        for (int r = 0; r < 4; ++r)
          rmax[h][r] = fmaxf(rmax[h][r], __shfl_xor(rmax[h][r], msk));
#pragma unroll
    for (int h = 0; h < 2; ++h)
#pragma unroll
      for (int r = 0; r < 4; ++r) {
        float mn = fmaxf(m_run[h][r], rmax[h][r]);
        float fr = exp2f(m_run[h][r] - mn);
        m_run[h][r] = mn;
        lsum[h][r] *= fr;
        Ov[h][0][r] *= fr;
        Ov[h][1][r] *= fr;
      }
  }

#pragma unroll
  for (int h = 0; h < 2; ++h)
#pragma unroll
    for (int r = 0; r < 4; ++r) {
      const float m = m_run[h][r];
      float p0 = exp2f(A[h][0][r] - m);
      float p1 = exp2f(A[h][1][r] - m);
      float p2 = exp2f(A[h][2][r] - m);
      float p3 = exp2f(A[h][3][r] - m);
      lsum[h][r] += (p0 + p1) + (p2 + p3);
      short4v pb;
      pb[0] = (short)f2bf(p0); pb[1] = (short)f2bf(p1);
      pb[2] = (short)f2bf(p2); pb[3] = (short)f2bf(p3);
      *reinterpret_cast<short4v*>(&Psw[h * 1152 + (g * 4 + r) * 72 + li * 4]) = pb;
    }

  const u16* vt = Vtg + tn * 64;
#pragma unroll
  for (int ks2 = 0; ks2 < 2; ++ks2) {
    short8v a0 = *reinterpret_cast<const short8v*>(&Psw[0 * 1152 + li * 72 + ks2 * 32 + g * 8]);
    short8v a1 = *reinterpret_cast<const short8v*>(&Psw[1 * 1152 + li * 72 + ks2 * 32 + g * 8]);
    short8v b0 = *reinterpret_cast<const short8v*>(&vt[li * 4096 + ks2 * 32 + g * 8]);
    short8v b1 = *reinterpret_cast<const short8v*>(&vt[(16 + li) * 4096 + ks2 * 32 + g * 8]);
    Ov[0][0] = __builtin_amdgcn_mfma_f32_16x16x32_bf16(a0, b0, Ov[0][0], 0, 0, 0);
    Ov[0][1] = __builtin_amdgcn_mfma_f32_16x16x32_bf16(a0, b1, Ov[0][1], 0, 0, 0);
    Ov[1][0] = __builtin_amdgcn_mfma_f32_16x16x32_bf16(a1, b0, Ov[1][0], 0, 0, 0);
    Ov[1][1] = __builtin_amdgcn_mfma_f32_16x16x32_bf16(a1, b1, Ov[1][1], 0, 0, 0);
  }
}

// ---------------------------------------------------------------------------
// main: 256 blocks x 256 threads, 128 queries/block (32/wave), flash over
// 64-page tiles; K double-buffered in LDS via global_load_lds, one barrier
// per tile, QK(t+1) overlapped with softmax/PV(t).
// ---------------------------------------------------------------------------
__global__ __launch_bounds__(256, 1) void mmu_main(
    const float* __restrict__ vpb_g, const float* __restrict__ W1g,
    const float* __restrict__ b1g, const float* __restrict__ W2g,
    const float* __restrict__ b2g, const float* __restrict__ temp_g,
    const u16* __restrict__ Kg, const u16* __restrict__ Vtg,
    float* __restrict__ outp) {
  __shared__ __align__(16) u16 Ks2[2][8192];      // 32768 B (vpb_s overlays pre-loop)
  __shared__ __align__(16) u16 Qs[QB * QS_LD];    // 34816 B
  __shared__ __align__(16) char unB[26624];       // W1s+hs (MLP)  ||  Ps (loop)
  float* W1s = (float*)unB;                       // [20][128]
  float* hs  = (float*)(unB + 10240);             // [32][128]
  u16*  Ps   = (u16*)unB;                         // 4 waves x 2 h x [16][72]
  float* vpb_s = (float*)(&Ks2[0][0]);            // [128][20] pre-loop only

  const int tid = threadIdx.x;
  const int q0 = blockIdx.x * QB;
  const float invt = 1.0f / fmaxf(fabsf(temp_g[0]), 0.1f);
  const float c2 = invt * 1.4426950408889634f;
  const u16 c2h = f2bf(c2);
  const u16 c2l = f2bf(c2 - bf2f(c2h));

  for (int i = tid; i < QB * 20; i += 256) vpb_s[i] = vpb_g[q0 * 20 + i];
  for (int i = tid; i < 20 * 128; i += 256) W1s[i] = W1g[i];
  __syncthreads();

  // Q cols 64..127: [c2v_hi | c2v_lo | c2v_hi | c2_hi c2_lo c2_hi 0]
  for (int i = tid; i < QB * 64; i += 256) {
    int q = i >> 6, c = 64 + (i & 63);
    u16 bits;
    if (c < 84) bits = f2bf(c2 * vpb_s[q * 20 + c - 64]);
    else if (c < 104) { float v = c2 * vpb_s[q * 20 + c - 84]; u16 hi = f2bf(v); bits = f2bf(v - bf2f(hi)); }
    else if (c < 124) bits = f2bf(c2 * vpb_s[q * 20 + c - 104]);
    else if (c == 124 || c == 126) bits = c2h;
    else if (c == 125) bits = c2l;
    else bits = 0;
    Qs[q * QS_LD + c] = bits;
  }

  // MLP -> Q cols 0..63 (scaled by c2), 4 chunks of 32 rows
  for (int half = 0; half < 4; ++half) {
    const int qb = half * 32;
    for (int i = tid; i < 32 * 128; i += 256) {
      int q = i >> 7, cc = i & 127;
      float acc = b1g[cc];
#pragma unroll
      for (int j = 0; j < 20; ++j) acc += vpb_s[(qb + q) * 20 + j] * W1s[j * 128 + cc];
      hs[i] = 0.5f * acc * (1.0f + erff(acc * 0.70710678118654752f));
    }
    __syncthreads();
    for (int i = tid; i < 32 * 64; i += 256) {
      int q = i >> 6, k = i & 63;
      float acc = b2g[k];
      for (int c = 0; c < 128; ++c) acc += hs[q * 128 + c] * W2g[c * 64 + k];
      Qs[(qb + q) * QS_LD + k] = f2bf(c2 * acc);
    }
    __syncthreads();
  }
  // vpb_s / W1s / hs dead from here.

  const int lane = tid & 63, w = tid >> 6, g = lane >> 4, li = lane & 15;
  u16* Psw = Ps + w * 2304;

  short8v qf[2][4];
#pragma unroll
  for (int h = 0; h < 2; ++h)
#pragma unroll
    for (int ks = 0; ks < 4; ++ks)
      qf[h][ks] = *reinterpret_cast<const short8v*>(
          &Qs[(w * 32 + h * 16 + li) * QS_LD + ks * 32 + g * 8]);

  float4v accA[2][4], accB[2][4];
  float4v Ov[2][2] = {{{0.f,0.f,0.f,0.f},{0.f,0.f,0.f,0.f}},
                      {{0.f,0.f,0.f,0.f},{0.f,0.f,0.f,0.f}}};
  float m_run[2][4] = {{-1e30f,-1e30f,-1e30f,-1e30f},{-1e30f,-1e30f,-1e30f,-1e30f}};
  float lsum[2][4] = {{0.f,0.f,0.f,0.f},{0.f,0.f,0.f,0.f}};

#define STAGE(tn, sb) {                                                    \
    const char* gsrc_ = (const char*)Kg + ((size_t)(tn) << 14) + (tid << 4); \
    u16* ld_ = &Ks2[sb][tid * 8];                                          \
    gl_lds16(gsrc_,         ld_);                                          \
    gl_lds16(gsrc_ + 4096,  ld_ + 2048);                                   \
    gl_lds16(gsrc_ + 8192,  ld_ + 4096);                                   \
    gl_lds16(gsrc_ + 12288, ld_ + 6144);                                   \
  }

  STAGE(0, 0);
  __syncthreads();              // tile 0 staged (drains own vmcnt + barrier)
  STAGE(1, 1);
  readqk(&Ks2[0][0], qf, accA, li, g);

  for (int tt = 0; tt < 62; tt += 2) {
    __syncthreads();            // tile tt+1 staged; all waves done with buf0
    STAGE(tt + 2, 0);
    readqk(&Ks2[1][0], qf, accB, li, g);          // QK(tt+1)
    smpv(accA, m_run, lsum, Ov, Psw, Vtg, tt, li, g);   // softmax+PV(tt)

    __syncthreads();            // tile tt+2 staged; all waves done with buf1
    STAGE(tt + 3, 1);
    readqk(&Ks2[0][0], qf, accA, li, g);          // QK(tt+2)
    smpv(accB, m_run, lsum, Ov, Psw, Vtg, tt + 1, li, g);
  }
  __syncthreads();              // tile 63 staged
  readqk(&Ks2[1][0], qf, accB, li, g);
  smpv(accA, m_run, lsum, Ov, Psw, Vtg, 62, li, g);
  smpv(accB, m_run, lsum, Ov, Psw, Vtg, 63, li, g);
#undef STAGE

  // reduce lsum over the 16 page-lanes, normalize, write out
#pragma unroll
  for (int msk = 1; msk <= 8; msk <<= 1)
#pragma unroll
    for (int h = 0; h < 2; ++h)
#pragma unroll
      for (int r = 0; r < 4; ++r) lsum[h][r] += __shfl_xor(lsum[h][r], msk);

#pragma unroll
  for (int h = 0; h < 2; ++h)
#pragma unroll
    for (int r = 0; r < 4; ++r) {
      const float inv = 1.0f / lsum[h][r];
      const int q = q0 + w * 32 + h * 16 + g * 4 + r;
      outp[q * 20 + li] = Ov[h][0][r] * inv;               // vcols 0..15
      const int vc = 16 + li;
      const float v1 = Ov[h][1][r] * inv;
      if (vc < 20) outp[q * 20 + vc] = v1;                 // vcols 16..19
      else if (vc == 20) outp[BATCH * 20 + q] = v1;        // perms[:,0]
      else if (vc < 24) outp[BATCH * 21 + q * 3 + (vc - 21)] = v1;  // perms[:,1:4]
    }
}

extern "C" void kernel_launch(void* const* d_in, const int* in_sizes, int n_in,
                              void* d_out, int out_size, void* d_ws, size_t ws_size,
                              hipStream_t stream) {
  const float* vpb = (const float*)d_in[0];
  const float* pk  = (const float*)d_in[1];
  const float* vp  = (const float*)d_in[2];
  const float* ph  = (const float*)d_in[3];
  const float* pr  = (const float*)d_in[4];
  const float* W1  = (const float*)d_in[5];
  const float* b1  = (const float*)d_in[6];
  const float* W2  = (const float*)d_in[7];
  const float* b2  = (const float*)d_in[8];
  const float* tp  = (const float*)d_in[9];

  u16* Kg  = (u16*)d_ws;                               // 1,048,576 B
  u16* Vtg = (u16*)((char*)d_ws + PAGES * 128 * 2);    //   262,144 B
  float* outp = (float*)d_out;

  hipLaunchKernelGGL(prep, dim3(768), dim3(256), 0, stream, pk, vp, ph, pr, Kg, Vtg);
  hipLaunchKernelGGL(mmu_main, dim3(256), dim3(256), 0, stream,
                     vpb, W1, b1, W2, b2, tp, Kg, Vtg, outp);
}